// Round 11
// baseline (221.250 us; speedup 1.0000x reference)
//
#include <hip/hip_runtime.h>
#include <stdint.h>

#define DIMD 512
#define ROWS 65536

#define GRID  1024
#define BLOCK 256
#define WPB   4                 // waves per block
#define RPW   16                // rows per wave (64 rows/block)
#define LDSR  3                 // rows per wave parked in LDS (12/block)

typedef float vfloat4 __attribute__((ext_vector_type(4)));

__device__ __forceinline__ float dist8(const float4 wa, const float4 wb,
                                       const float4 xa, const float4 xb)
{
    float s = 0.0f, t;
    t = wa.x - xa.x; s = fmaf(t, t, s);
    t = wa.y - xa.y; s = fmaf(t, t, s);
    t = wa.z - xa.z; s = fmaf(t, t, s);
    t = wa.w - xa.w; s = fmaf(t, t, s);
    t = wb.x - xb.x; s = fmaf(t, t, s);
    t = wb.y - xb.y; s = fmaf(t, t, s);
    t = wb.z - xb.z; s = fmaf(t, t, s);
    t = wb.w - xb.w; s = fmaf(t, t, s);
    return s;
}

__device__ __forceinline__ void update_row(const float4 wa, const float4 wb,
                                           const float4 xa, const float4 xb,
                                           int row, unsigned bmu,
                                           float bi, float bj,
                                           float alpha_op, float inv_s2,
                                           float* __restrict__ winner,
                                           float* __restrict__ new_weights,
                                           int lane)
{
    const float di = (float)(row >> 8) - bi;
    const float dj = (float)(row & 255) - bj;
    const float coef = alpha_op * __expf(-(di * di + dj * dj) * inv_s2);

    vfloat4 oa, ob;
    oa.x = fmaf(coef, xa.x - wa.x, wa.x);
    oa.y = fmaf(coef, xa.y - wa.y, wa.y);
    oa.z = fmaf(coef, xa.z - wa.z, wa.z);
    oa.w = fmaf(coef, xa.w - wa.w, wa.w);
    ob.x = fmaf(coef, xb.x - wb.x, wb.x);
    ob.y = fmaf(coef, xb.y - wb.y, wb.y);
    ob.z = fmaf(coef, xb.z - wb.z, wb.z);
    ob.w = fmaf(coef, xb.w - wb.w, wb.w);

    vfloat4* o4 = reinterpret_cast<vfloat4*>(new_weights + (size_t)row * DIMD);
    __builtin_nontemporal_store(oa, o4 + lane);
    __builtin_nontemporal_store(ob, o4 + lane + 64);

    if (row == (int)bmu) {
        float4* wn = reinterpret_cast<float4*>(winner);
        wn[lane]      = wa;   // OLD weights row
        wn[lane + 64] = wb;
    }
}

// ===========================================================================
// Single-dispatch fused SOM. NON-cooperative; the spin barrier is deadlock-
// free BY CONSTRUCTION: __launch_bounds__(256,8) forces the 64-VGPR cap
// (observed hard on this toolchain under both interpretations of arg 2) ->
// >=6 blocks/CU fit (LDS 24.6KB -> 6/CU; VGPR -> 8/CU); grid 1024 needs only
// 4/CU average (capacity 1536, or 171 of 256 CUs). All blocks co-resident.
// Phase 1: distances for 64 rows/block, 12 parked in LDS. Phase 2 (after
// device barrier): fused update; 12 rows from LDS, 52 re-read (L3-warm).
// ===========================================================================
__global__ __launch_bounds__(BLOCK, 8) void som_fused(
    const float* __restrict__ x,
    const float* __restrict__ w,
    const int* __restrict__ it_ptr,
    unsigned long long* __restrict__ slots,   // [GRID], no init needed
    int* __restrict__ done,                   // [1], memset 0 per call
    float* __restrict__ out)
{
    __shared__ float lds[WPB * LDSR * DIMD];      // 24576 B
    __shared__ unsigned long long sred[WPB];      // +32 B

    const int lane = threadIdx.x & 63;
    const int wave = threadIdx.x >> 6;
    const int row0 = (blockIdx.x * WPB + wave) * RPW;

    const float4* x4 = reinterpret_cast<const float4*>(x);
    const float4 xa = x4[lane];
    const float4 xb = x4[lane + 64];
    const float4* w4 = reinterpret_cast<const float4*>(w);

    unsigned long long best = ~0ull;
    float d[8];

    // ---- phase 1, batch A: rows 0..7 (0..2 parked in LDS) ----
    #pragma unroll
    for (int r = 0; r < 8; ++r) {
        const float4* p = w4 + (size_t)(row0 + r) * (DIMD / 4);
        const float4 wa  = p[lane];
        const float4 wbv = p[lane + 64];
        if (r < LDSR) {
            float4* dst = reinterpret_cast<float4*>(
                lds + (wave * LDSR + r) * DIMD);
            dst[lane]      = wa;
            dst[lane + 64] = wbv;
        }
        d[r] = dist8(wa, wbv, xa, xb);
    }
    #pragma unroll
    for (int off = 32; off > 0; off >>= 1) {
        #pragma unroll
        for (int r = 0; r < 8; ++r) d[r] += __shfl_xor(d[r], off, 64);
    }
    #pragma unroll
    for (int r = 0; r < 8; ++r) {
        const unsigned long long key =
            (((unsigned long long)__float_as_uint(d[r])) << 32) |
            (unsigned long long)(unsigned)(row0 + r);
        best = (key < best) ? key : best;
    }

    // ---- phase 1, batch B: rows 8..15 ----
    #pragma unroll
    for (int r = 0; r < 8; ++r) {
        const float4* p = w4 + (size_t)(row0 + 8 + r) * (DIMD / 4);
        d[r] = dist8(p[lane], p[lane + 64], xa, xb);
    }
    #pragma unroll
    for (int off = 32; off > 0; off >>= 1) {
        #pragma unroll
        for (int r = 0; r < 8; ++r) d[r] += __shfl_xor(d[r], off, 64);
    }
    #pragma unroll
    for (int r = 0; r < 8; ++r) {
        const unsigned long long key =
            (((unsigned long long)__float_as_uint(d[r])) << 32) |
            (unsigned long long)(unsigned)(row0 + 8 + r);
        best = (key < best) ? key : best;
    }

    // ---- block-best -> slots[blockIdx], arrive, spin (thread0 only) ----
    if (lane == 0) sred[wave] = best;
    __syncthreads();
    if (threadIdx.x == 0) {
        unsigned long long b = sred[0];
        #pragma unroll
        for (int i = 1; i < WPB; ++i) b = (sred[i] < b) ? sred[i] : b;
        __hip_atomic_store(&slots[blockIdx.x], b, __ATOMIC_RELEASE,
                           __HIP_MEMORY_SCOPE_AGENT);
        __hip_atomic_fetch_add(done, 1, __ATOMIC_ACQ_REL,
                               __HIP_MEMORY_SCOPE_AGENT);
        while (__hip_atomic_load(done, __ATOMIC_ACQUIRE,
                                 __HIP_MEMORY_SCOPE_AGENT) < GRID) {
            __builtin_amdgcn_s_sleep(2);
        }
        __threadfence();
    }
    __syncthreads();

    // ---- global argmin: all threads stride the 1024 slots ----
    unsigned long long g = ~0ull;
    #pragma unroll
    for (int k = 0; k < GRID / BLOCK; ++k) {
        const unsigned long long v = slots[k * BLOCK + threadIdx.x];
        g = (v < g) ? v : g;
    }
    #pragma unroll
    for (int off = 32; off > 0; off >>= 1) {
        const unsigned long long o = __shfl_xor(g, off, 64);
        g = (o < g) ? o : g;
    }
    if (lane == 0) sred[wave] = g;
    __syncthreads();
    g = sred[0];
    #pragma unroll
    for (int i = 1; i < WPB; ++i) g = (sred[i] < g) ? sred[i] : g;

    const unsigned bmu = (unsigned)(g & 0xFFFFFFFFull);
    const float bi = (float)(bmu >> 8);
    const float bj = (float)(bmu & 255u);

    // scalar decay math in double, matching Python semantics
    const double itd      = (double)(*it_ptr);
    const double lr       = 1.0 - itd / 1000.0;
    const float  alpha_op = (float)(0.3 * lr);
    const double sigma_op = 128.0 * lr;           // SIGMA = max(M,N)/2
    const float  inv_s2   = (float)(1.0 / (sigma_op * sigma_op));

    float* winner      = out;          // first 512 floats
    float* new_weights = out + DIMD;   // then 65536 x 512

    // ---- phase 2: global re-read rows first (start HBM streams ASAP) ----
    #pragma unroll 2
    for (int r = LDSR; r < RPW; ++r) {
        const float4* p = w4 + (size_t)(row0 + r) * (DIMD / 4);
        update_row(p[lane], p[lane + 64], xa, xb, row0 + r, bmu,
                   bi, bj, alpha_op, inv_s2, winner, new_weights, lane);
    }

    // ---- phase 2: LDS-parked rows ----
    #pragma unroll
    for (int r = 0; r < LDSR; ++r) {
        const float4* src = reinterpret_cast<const float4*>(
            lds + (wave * LDSR + r) * DIMD);
        update_row(src[lane], src[lane + 64], xa, xb, row0 + r, bmu,
                   bi, bj, alpha_op, inv_s2, winner, new_weights, lane);
    }
}

extern "C" void kernel_launch(void* const* d_in, const int* in_sizes, int n_in,
                              void* d_out, int out_size, void* d_ws, size_t ws_size,
                              hipStream_t stream) {
    const float* x       = (const float*)d_in[0];
    const float* weights = (const float*)d_in[1];
    // d_in[2] = y (unused by the math)
    const int*   it_ptr  = (const int*)d_in[3];

    float* out = (float*)d_out;

    // ws layout: [0,4) done counter | [64, 64+8*GRID) slots
    int*                done  = (int*)d_ws;
    unsigned long long* slots = (unsigned long long*)((char*)d_ws + 64);

    hipMemsetAsync(done, 0, sizeof(int), stream);   // reset barrier each call

    som_fused<<<GRID, BLOCK, 0, stream>>>(x, weights, it_ptr, slots, done, out);
}